// Round 9
// baseline (826.520 us; speedup 1.0000x reference)
//
#include <hip/hip_runtime.h>
#include <hip/hip_cooperative_groups.h>
#include <cstdint>

// DynamicConvAttention: B=4, S=2048, D=1024, NH=16 (groups), K=3
// f32 I/O, bf16 MFMA internal. PRIMARY: 2 launches (prep + cooperative
// fused_all). Fallback: r14's 6-launch flow if coop launch unavailable.
//
// r17: entire post-prep pipeline fused into ONE cooperative kernel
// (512 blocks = exactly 2/CU resident, grid.sync() between phases):
//   A: QKV 1536 tiles (3/blk; z=2 writes V TRANSPOSED into vt)
//   B: scores 1024 tiles (P'=exp(s/32) + rowsum atomics) + conv 1024 (2+2/blk)
//   C: PV 512 tiles (normalize by 1/rowsum)
//   D: ln2 8192 rows (16/blk): combined = LN2(LN1(conv)+attn)
//   E: out 512 tiles: out = combined@Wo + bo + x
// Each grid.sync replaces a ~15us launch boundary. Numerics identical to
// r14 (same tiles/epilogues). If hipLaunchCooperativeKernel errors, the
// proven separate-launch r14 sequence runs instead.
//
// ws: wT[0,8M) | qkvb[8M,+12K) | rsum[8M+16K,+32K) | Q[9,25M) | K[25,41M)
//     | V[41,57M)=conv | Pw[57,73M) ; d_out: xb/Pd [0,16Mi) | vt [16Mi,32Mi)

#define DEV __device__ __forceinline__

namespace cg = cooperative_groups;

typedef unsigned short u16;
typedef __attribute__((ext_vector_type(8))) short bf16x8;
typedef __attribute__((ext_vector_type(4))) float f32x4;

static const int Sn = 2048, Dn = 1024;

DEV float bf2f(u16 u) { union { unsigned int i; float f; } w; w.i = ((unsigned int)u) << 16; return w.f; }
DEV u16 f2bf(float f) {
  union { float f; unsigned int i; } w; w.f = f;
  unsigned int x = w.i;
  return (u16)((x + 0x7FFFu + ((x >> 16) & 1u)) >> 16);
}

DEV void gload_lds16(const u16* gsrc, u16* lds_dst) {
  __builtin_amdgcn_global_load_lds(
      (const __attribute__((address_space(1))) void*)gsrc,
      (__attribute__((address_space(3))) void*)lds_dst,
      16, 0, 0);
}

DEV float block_allreduce_sum(float v, float* red, int tid) {
  #pragma unroll
  for (int o = 32; o > 0; o >>= 1) v += __shfl_down(v, o, 64);
  __syncthreads();
  if ((tid & 63) == 0) red[tid >> 6] = v;
  __syncthreads();
  return red[0] + red[1] + red[2] + red[3];
}

DEV float block_allreduce_max(float v, float* red, int tid) {
  #pragma unroll
  for (int o = 32; o > 0; o >>= 1) v = fmaxf(v, __shfl_down(v, o, 64));
  __syncthreads();
  if ((tid & 63) == 0) red[tid >> 6] = v;
  __syncthreads();
  return fmaxf(fmaxf(red[0], red[1]), fmaxf(red[2], red[3]));
}

// ---- core 128x128 NT GEMM tile: fills acc[4][4]; smem = 16384 u16 ----
DEV void gemm_tile_acc(const u16* __restrict__ A, const u16* __restrict__ B,
                       int lda, int ldb, int K, long m0, long n0,
                       u16* smem, int tid, f32x4 acc[4][4]) {
  u16* sA0 = smem;
  u16* sB0 = smem + 2 * 128 * 32;
  int lane = tid & 63, wv = tid >> 6;
  int quad = lane >> 4, lm = lane & 15;
  int wr = wv >> 1, wc = wv & 1;
  int srow = wv * 16 + (lane >> 2);
  int sch = (lane & 3) * 8;
  const u16* Ap = A + (m0 + srow) * (long)lda + sch;
  const u16* Bp = B + (n0 + srow) * (long)ldb + sch;
  const int lofs = wv * 16 * 32;
  for (int k0 = 0; k0 < K; k0 += 64) {
    #pragma unroll
    for (int h = 0; h < 2; h++) {
      int kh = k0 + h * 32;
      gload_lds16(Ap + kh, &sA0[h * 128 * 32 + lofs]);
      gload_lds16(Ap + 64 * (long)lda + kh, &sA0[h * 128 * 32 + lofs + 64 * 32]);
      gload_lds16(Bp + kh, &sB0[h * 128 * 32 + lofs]);
      gload_lds16(Bp + 64 * (long)ldb + kh, &sB0[h * 128 * 32 + lofs + 64 * 32]);
    }
    __syncthreads();
    #pragma unroll
    for (int h = 0; h < 2; h++) {
      bf16x8 af[4], bfr[4];
      #pragma unroll
      for (int mi = 0; mi < 4; mi++)
        af[mi] = *(const bf16x8*)&sA0[h * 128 * 32 + (wr * 64 + mi * 16 + lm) * 32 + quad * 8];
      #pragma unroll
      for (int ni = 0; ni < 4; ni++)
        bfr[ni] = *(const bf16x8*)&sB0[h * 128 * 32 + (wc * 64 + ni * 16 + lm) * 32 + quad * 8];
      #pragma unroll
      for (int mi = 0; mi < 4; mi++)
        #pragma unroll
        for (int ni = 0; ni < 4; ni++)
          acc[mi][ni] = __builtin_amdgcn_mfma_f32_16x16x32_bf16(af[mi], bfr[ni], acc[mi][ni], 0, 0, 0);
    }
    __syncthreads();
  }
}

// ---- grouped conv body; smem = 22160 u16 ----
DEV void conv_body(u16* smem, int r, int tid,
                   const float* __restrict__ x, const float* __restrict__ cw,
                   const float* __restrict__ cb, u16* __restrict__ convo) {
  u16 (*sx)[72] = (u16(*)[72])smem;
  u16 (*sw)[200] = (u16(*)[200])(smem + 9360);
  int s0 = (r & 15) * 128;
  int g = (r >> 4) & 15;
  int b = r >> 8;
  int lane = tid & 63, wv = tid >> 6;
  int quad = lane >> 4, lm = lane & 15;
  for (int idx = tid; idx < 64 * 192; idx += 256) {
    int oc = idx / 192, k = idx - oc * 192;
    int t2 = k >> 6, i = k & 63;
    sw[oc][k] = f2bf(cw[((long)(g * 64 + oc)) * 192 + i * 3 + t2]);
  }
  for (int idx = tid; idx < 130 * 16; idx += 256) {
    int rr = idx >> 4, c4 = (idx & 15) * 4;
    int s = s0 - 1 + rr;
    ushort4 v;
    if (s >= 0 && s < Sn) {
      float4 f = *(const float4*)&x[((long)b * Sn + s) * Dn + g * 64 + c4];
      v.x = f2bf(f.x); v.y = f2bf(f.y); v.z = f2bf(f.z); v.w = f2bf(f.w);
    } else { v.x = 0; v.y = 0; v.z = 0; v.w = 0; }
    *(ushort4*)&sx[rr][c4] = v;
  }
  __syncthreads();
  f32x4 acc[2][4] = {};
  #pragma unroll
  for (int ks = 0; ks < 6; ks++) {
    int t2 = ks >> 1;
    int i0 = (ks & 1) * 32 + quad * 8;
    bf16x8 a0 = *(const bf16x8*)&sx[wv * 32 + lm + t2][i0];
    bf16x8 a1 = *(const bf16x8*)&sx[wv * 32 + 16 + lm + t2][i0];
    #pragma unroll
    for (int nf = 0; nf < 4; nf++) {
      bf16x8 bf = *(const bf16x8*)&sw[nf * 16 + lm][ks * 32 + quad * 8];
      acc[0][nf] = __builtin_amdgcn_mfma_f32_16x16x32_bf16(a0, bf, acc[0][nf], 0, 0, 0);
      acc[1][nf] = __builtin_amdgcn_mfma_f32_16x16x32_bf16(a1, bf, acc[1][nf], 0, 0, 0);
    }
  }
  #pragma unroll
  for (int mi = 0; mi < 2; mi++) {
    #pragma unroll
    for (int nf = 0; nf < 4; nf++) {
      int col = g * 64 + nf * 16 + lm;
      float bias = cb[col];
      #pragma unroll
      for (int rr = 0; rr < 4; rr++) {
        int row = wv * 32 + mi * 16 + quad * 4 + rr;
        convo[((long)b * Sn + s0 + row) * Dn + col] = f2bf(acc[mi][nf][rr] + bias);
      }
    }
  }
}

// ---- ln2 row: combined = LN2(LN1(conv)+attn), LN1 in f32 ----
DEV void ln2_row(const u16* __restrict__ conv, const u16* __restrict__ attn,
                 const float* __restrict__ gamma, const float* __restrict__ beta,
                 u16* __restrict__ out, long row, int tid, float* red) {
  long base = row * Dn + tid * 4;
  ushort4 cv = *(const ushort4*)&conv[base];
  float c0 = bf2f(cv.x), c1 = bf2f(cv.y), c2 = bf2f(cv.z), c3 = bf2f(cv.w);
  float4 gv = *(const float4*)&gamma[tid * 4];
  float4 bev = *(const float4*)&beta[tid * 4];
  float s1 = block_allreduce_sum(c0 + c1 + c2 + c3, red, tid);
  float mean1 = s1 * (1.0f / 1024.0f);
  float d0 = c0 - mean1, d1 = c1 - mean1, d2 = c2 - mean1, d3 = c3 - mean1;
  float sq1 = block_allreduce_sum(d0 * d0 + d1 * d1 + d2 * d2 + d3 * d3, red, tid);
  float inv1 = 1.0f / (sqrtf(sq1 * (1.0f / 1023.0f)) + 1e-6f);
  ushort4 av = *(const ushort4*)&attn[base];
  float v0 = gv.x * d0 * inv1 + bev.x + bf2f(av.x);
  float v1 = gv.y * d1 * inv1 + bev.y + bf2f(av.y);
  float v2 = gv.z * d2 * inv1 + bev.z + bf2f(av.z);
  float v3 = gv.w * d3 * inv1 + bev.w + bf2f(av.w);
  float s2 = block_allreduce_sum(v0 + v1 + v2 + v3, red, tid);
  float mean2 = s2 * (1.0f / 1024.0f);
  float e0 = v0 - mean2, e1 = v1 - mean2, e2 = v2 - mean2, e3 = v3 - mean2;
  float sq2 = block_allreduce_sum(e0 * e0 + e1 * e1 + e2 * e2 + e3 * e3, red, tid);
  float inv2 = 1.0f / (sqrtf(sq2 * (1.0f / 1023.0f)) + 1e-6f);
  ushort4 o;
  o.x = f2bf(gv.x * e0 * inv2 + bev.x);
  o.y = f2bf(gv.y * e1 * inv2 + bev.y);
  o.z = f2bf(gv.z * e2 * inv2 + bev.z);
  o.w = f2bf(gv.w * e3 * inv2 + bev.w);
  *(ushort4*)&out[base] = o;
}

// ================= prep_all: weights T + bias + rowsum zero + x cvt ========
__global__ __launch_bounds__(256)
void prep_all(const float* __restrict__ Wq, const float* __restrict__ Wk,
              const float* __restrict__ Wv, const float* __restrict__ Wo,
              u16* __restrict__ wT,
              const float* __restrict__ bq, const float* __restrict__ bv,
              float* __restrict__ qkvb, float* __restrict__ rowsum,
              const float* __restrict__ x, u16* __restrict__ xb) {
  __shared__ u16 sm[64][68];
  int blk = blockIdx.x;
  int tid = threadIdx.x;
  if (blk < 1024) {
    int w = blk >> 8, t = blk & 255;
    const float* src = (w == 0) ? Wq : (w == 1) ? Wk : (w == 2) ? Wv : Wo;
    u16* dst = wT + (size_t)w * 1048576u;
    int i0 = (t >> 4) << 6, j0 = (t & 15) << 6;
    int tx = tid & 15, r0 = tid >> 4;
    #pragma unroll
    for (int rr = r0; rr < 64; rr += 16) {
      float4 v = *(const float4*)&src[(long)(i0 + rr) * 1024 + j0 + tx * 4];
      sm[rr][tx*4+0] = f2bf(v.x); sm[rr][tx*4+1] = f2bf(v.y);
      sm[rr][tx*4+2] = f2bf(v.z); sm[rr][tx*4+3] = f2bf(v.w);
    }
    __syncthreads();
    #pragma unroll
    for (int cc = r0; cc < 64; cc += 16) {
      ushort4 o;
      o.x = sm[tx*4+0][cc]; o.y = sm[tx*4+1][cc];
      o.z = sm[tx*4+2][cc]; o.w = sm[tx*4+3][cc];
      *(ushort4*)&dst[(long)(j0 + cc) * 1024 + i0 + tx * 4] = o;
    }
  } else if (blk == 1024) {
    for (int j = tid; j < 3072; j += 256) {
      float v = 0.0f;
      if (j < 1024) v = bq[j];
      else if (j >= 2048) v = bv[j - 2048];
      qkvb[j] = v;
    }
    for (int j = tid; j < 8192; j += 256) rowsum[j] = 0.0f;
  } else {
    int i = (blk - 1025) * 1024 + tid * 4;
    float4 v = *(const float4*)&x[i];
    ushort4 o;
    o.x = f2bf(v.x); o.y = f2bf(v.y); o.z = f2bf(v.z); o.w = f2bf(v.w);
    *(ushort4*)&xb[i] = o;
  }
}

// =============== fused_all: cooperative QKV->scores+conv->PV->ln2->out =====
struct FusedArgs {
  const u16* xb; const u16* wT; const float* qkvb;
  u16* Qb; u16* Kb; u16* vt;
  u16* Pd; u16* Pw; float* rsum;
  const float* x; const float* cw; const float* cb; u16* conv;
  u16* attn; const float* gamma; const float* beta; u16* combined;
  const float* bo; float* out;
};

__global__ __launch_bounds__(256, 2)
void fused_all(FusedArgs a) {
  __shared__ u16 smem[22160];
  __shared__ float red[4];
  cg::grid_group grid = cg::this_grid();
  int blk = blockIdx.x;
  int tid = threadIdx.x;
  int nb = (int)gridDim.x;
  int lane = tid & 63, wv = tid >> 6;
  int quad = lane >> 4, lm = lane & 15;
  int wr = wv >> 1, wc = wv & 1;
  const long PBS = (long)Sn * Sn;

  // ---------- phase A: QKV, 1536 tiles ----------
  for (int it = blk; it < 1536; it += nb) {
    int z = it >> 9, rem = it & 511;
    long m0 = (long)(rem & 63) * 128, n0 = (long)(rem >> 6) * 128;
    f32x4 acc[4][4] = {};
    gemm_tile_acc(a.xb, a.wT + (long)z * 1048576, 1024, 1024, 1024,
                  m0, n0, smem, tid, acc);
    if (z == 2) {
      int b = (int)(m0 >> 11);
      long s0 = (m0 & 2047) + wr * 64 + quad * 4;
      #pragma unroll
      for (int ni = 0; ni < 4; ni++) {
        int col = (int)n0 + wc * 64 + ni * 16 + lm;
        float bv = a.qkvb[2048 + col];
        u16* vrow = a.vt + ((long)b * 1024 + col) * 2048;
        #pragma unroll
        for (int mi = 0; mi < 4; mi++) {
          ushort4 o;
          o.x = f2bf(acc[mi][ni][0] + bv);
          o.y = f2bf(acc[mi][ni][1] + bv);
          o.z = f2bf(acc[mi][ni][2] + bv);
          o.w = f2bf(acc[mi][ni][3] + bv);
          *(ushort4*)&vrow[s0 + mi * 16] = o;
        }
      }
    } else {
      u16* C = (z == 0) ? a.Qb : a.Kb;
      #pragma unroll
      for (int mi = 0; mi < 4; mi++) {
        #pragma unroll
        for (int ni = 0; ni < 4; ni++) {
          int col = (int)n0 + wc * 64 + ni * 16 + lm;
          float bv = a.qkvb[z * 1024 + col];
          #pragma unroll
          for (int r = 0; r < 4; r++) {
            long rowg = m0 + wr * 64 + mi * 16 + quad * 4 + r;
            C[rowg * 1024 + col] = f2bf(acc[mi][ni][r] + bv);
          }
        }
      }
    }
  }
  __threadfence();
  grid.sync();

  // ---------- phase B: scores 1024 + conv 1024 ----------
  for (int it = blk; it < 2048; it += nb) {
    if (it < 1024) {
      int z = it >> 8;
      long m0 = (long)(it & 15) * 128, n0 = (long)((it >> 4) & 15) * 128;
      u16* C = (z < 2) ? a.Pd + (long)z * PBS : a.Pw + (long)(z - 2) * PBS;
      f32x4 acc[4][4] = {};
      gemm_tile_acc(a.Qb + (long)z * Sn * Dn, a.Kb + (long)z * Sn * Dn,
                    1024, 1024, 1024, m0, n0, smem, tid, acc);
      float psum[4][4];
      #pragma unroll
      for (int mi = 0; mi < 4; mi++)
        #pragma unroll
        for (int r = 0; r < 4; r++) psum[mi][r] = 0.0f;
      #pragma unroll
      for (int mi = 0; mi < 4; mi++) {
        #pragma unroll
        for (int ni = 0; ni < 4; ni++) {
          int col = (int)n0 + wc * 64 + ni * 16 + lm;
          #pragma unroll
          for (int r = 0; r < 4; r++) {
            long rowg = m0 + wr * 64 + mi * 16 + quad * 4 + r;
            float e = __expf(acc[mi][ni][r] * 0.03125f);
            psum[mi][r] += e;
            C[rowg * 2048 + col] = f2bf(e);
          }
        }
      }
      #pragma unroll
      for (int mi = 0; mi < 4; mi++)
        #pragma unroll
        for (int r = 0; r < 4; r++) {
          float v = psum[mi][r];
          v += __shfl_xor(v, 1, 64);
          v += __shfl_xor(v, 2, 64);
          v += __shfl_xor(v, 4, 64);
          v += __shfl_xor(v, 8, 64);
          psum[mi][r] = v;
        }
      if (lm == 0) {
        #pragma unroll
        for (int mi = 0; mi < 4; mi++)
          #pragma unroll
          for (int r = 0; r < 4; r++) {
            long rowg = m0 + wr * 64 + mi * 16 + quad * 4 + r;
            unsafeAtomicAdd(&a.rsum[(long)z * 2048 + rowg], psum[mi][r]);
          }
      }
    } else {
      conv_body(smem, it - 1024, tid, a.x, a.cw, a.cb, a.conv);
    }
    __syncthreads();
  }
  __threadfence();
  grid.sync();

  // ---------- phase C: PV 512 tiles ----------
  {
    int it = blk;
    int z = it >> 7;
    long m0 = (long)(it & 15) * 128, n0 = (long)((it >> 4) & 7) * 128;
    const u16* A = (z < 2) ? a.Pd + (long)z * PBS : a.Pw + (long)(z - 2) * PBS;
    const u16* B = a.vt + (long)z * Dn * Sn;
    u16* C = a.attn + (long)z * Sn * Dn;
    f32x4 acc[4][4] = {};
    gemm_tile_acc(A, B, 2048, 2048, 2048, m0, n0, smem, tid, acc);
    float inv[4][4];
    #pragma unroll
    for (int mi = 0; mi < 4; mi++)
      #pragma unroll
      for (int r = 0; r < 4; r++) {
        long rowg = m0 + wr * 64 + mi * 16 + quad * 4 + r;
        inv[mi][r] = 1.0f / a.rsum[(long)z * 2048 + rowg];
      }
    #pragma unroll
    for (int mi = 0; mi < 4; mi++) {
      #pragma unroll
      for (int ni = 0; ni < 4; ni++) {
        int col = (int)n0 + wc * 64 + ni * 16 + lm;
        #pragma unroll
        for (int r = 0; r < 4; r++) {
          long rowg = m0 + wr * 64 + mi * 16 + quad * 4 + r;
          C[rowg * 1024 + col] = f2bf(acc[mi][ni][r] * inv[mi][r]);
        }
      }
    }
  }
  __threadfence();
  grid.sync();

  // ---------- phase D: ln2, 8192 rows ----------
  for (int row = blk; row < 8192; row += nb)
    ln2_row(a.conv, a.attn, a.gamma, a.beta, a.combined, row, tid, red);
  __threadfence();
  grid.sync();

  // ---------- phase E: out = combined@Wo + bo + x, 512 tiles ----------
  {
    int it = blk;
    long m0 = (long)(it & 63) * 128, n0 = (long)(it >> 6) * 128;
    f32x4 acc[4][4] = {};
    gemm_tile_acc(a.combined, a.wT + 3ll * 1048576, 1024, 1024, 1024,
                  m0, n0, smem, tid, acc);
    #pragma unroll
    for (int mi = 0; mi < 4; mi++) {
      #pragma unroll
      for (int ni = 0; ni < 4; ni++) {
        int col = (int)n0 + wc * 64 + ni * 16 + lm;
        float bv = a.bo[col];
        #pragma unroll
        for (int r = 0; r < 4; r++) {
          long rowg = m0 + wr * 64 + mi * 16 + quad * 4 + r;
          a.out[rowg * 1024 + col] =
              acc[mi][ni][r] + bv + a.x[rowg * 1024 + col];
        }
      }
    }
  }
}

// ================= NT GEMM (fallback + out GEMM when coop fails) ===========
template<typename CT>
__global__ __launch_bounds__(256, 2)
void gemm_nt(const u16* __restrict__ A, const u16* __restrict__ A2, long Abs, int lda,
             const u16* __restrict__ B, long Bbs, int ldb,
             CT* __restrict__ C, CT* __restrict__ C2, long Cbs, int ldc,
             int zsplit, int K, float scale,
             const float* __restrict__ bias, int bias_bs,
             const float* __restrict__ res, long Rbs, int ldr,
             u16* __restrict__ vtout) {
  __shared__ u16 smem[4 * 128 * 32];
  int tid = threadIdx.x;
  int lane = tid & 63, wv = tid >> 6;
  int quad = lane >> 4, lm = lane & 15;
  int wr = wv >> 1, wc = wv & 1;
  long m0 = (long)blockIdx.x * 128, n0 = (long)blockIdx.y * 128;
  int z = blockIdx.z;
  if (z >= zsplit) { A = A2 + (long)(z - zsplit) * Abs; C = C2 + (long)(z - zsplit) * Cbs; }
  else             { A = A  + (long)z * Abs;            C = C  + (long)z * Cbs; }
  B += (long)z * Bbs;
  if (res) res += (long)z * Rbs;

  f32x4 acc[4][4] = {};
  gemm_tile_acc(A, B, lda, ldb, K, m0, n0, smem, tid, acc);

  if (sizeof(CT) == 2 && vtout && z == 2) {
    int b = (int)(m0 >> 11);
    long s0 = (m0 & 2047) + wr * 64 + quad * 4;
    #pragma unroll
    for (int ni = 0; ni < 4; ni++) {
      int col = (int)n0 + wc * 64 + ni * 16 + lm;
      float bv = bias ? bias[(long)z * bias_bs + col] : 0.0f;
      u16* vrow = vtout + ((long)b * 1024 + col) * 2048;
      #pragma unroll
      for (int mi = 0; mi < 4; mi++) {
        ushort4 o;
        o.x = f2bf(acc[mi][ni][0] * scale + bv);
        o.y = f2bf(acc[mi][ni][1] * scale + bv);
        o.z = f2bf(acc[mi][ni][2] * scale + bv);
        o.w = f2bf(acc[mi][ni][3] * scale + bv);
        *(ushort4*)&vrow[s0 + mi * 16] = o;
      }
    }
  } else {
    #pragma unroll
    for (int mi = 0; mi < 4; mi++) {
      #pragma unroll
      for (int ni = 0; ni < 4; ni++) {
        int col = (int)n0 + wc * 64 + ni * 16 + lm;
        float bv = bias ? bias[(long)z * bias_bs + col] : 0.0f;
        #pragma unroll
        for (int r = 0; r < 4; r++) {
          long rowg = m0 + wr * 64 + mi * 16 + quad * 4 + r;
          float v = acc[mi][ni][r] * scale + bv;
          if (res) v += res[rowg * (long)ldr + col];
          if constexpr (sizeof(CT) == 2) C[rowg * (long)ldc + col] = f2bf(v);
          else                           C[rowg * (long)ldc + col] = v;
        }
      }
    }
  }
}

// ====== post_qkv: scores (exp+rowsum) [+ V^T tiles for small-ws path] ======
__global__ __launch_bounds__(256, 2)
void post_qkv(int ngemm,
              const u16* __restrict__ Qb, const u16* __restrict__ Kb,
              u16* __restrict__ Pd, u16* __restrict__ Pw,
              const u16* __restrict__ Vb, u16* __restrict__ vt,
              float* __restrict__ rowsum) {
  __shared__ u16 smem[4 * 128 * 32];
  int blk = blockIdx.x;
  int tid = threadIdx.x;
  if (blk < ngemm) {
    int lane = tid & 63, wv = tid >> 6;
    int quad = lane >> 4, lm = lane & 15;
    int wr = wv >> 1, wc = wv & 1;
    int z = blk >> 8;
    long m0 = (long)(blk & 15) * 128, n0 = (long)((blk >> 4) & 15) * 128;
    u16* C = (z < 2) ? Pd + (long)z * Sn * Sn : Pw + (long)(z - 2) * Sn * Sn;
    f32x4 acc[4][4] = {};
    gemm_tile_acc(Qb + (long)z * Sn * Dn, Kb + (long)z * Sn * Dn,
                  1024, 1024, 1024, m0, n0, smem, tid, acc);
    float psum[4][4];
    #pragma unroll
    for (int mi = 0; mi < 4; mi++)
      #pragma unroll
      for (int r = 0; r < 4; r++) psum[mi][r] = 0.0f;
    #pragma unroll
    for (int mi = 0; mi < 4; mi++) {
      #pragma unroll
      for (int ni = 0; ni < 4; ni++) {
        int col = (int)n0 + wc * 64 + ni * 16 + lm;
        #pragma unroll
        for (int r = 0; r < 4; r++) {
          long rowg = m0 + wr * 64 + mi * 16 + quad * 4 + r;
          float e = __expf(acc[mi][ni][r] * 0.03125f);
          psum[mi][r] += e;
          C[rowg * 2048 + col] = f2bf(e);
        }
      }
    }
    #pragma unroll
    for (int mi = 0; mi < 4; mi++)
      #pragma unroll
      for (int r = 0; r < 4; r++) {
        float v = psum[mi][r];
        v += __shfl_xor(v, 1, 64);
        v += __shfl_xor(v, 2, 64);
        v += __shfl_xor(v, 4, 64);
        v += __shfl_xor(v, 8, 64);
        psum[mi][r] = v;
      }
    if (lm == 0) {
      #pragma unroll
      for (int mi = 0; mi < 4; mi++)
        #pragma unroll
        for (int r = 0; r < 4; r++) {
          long rowg = m0 + wr * 64 + mi * 16 + quad * 4 + r;
          unsafeAtomicAdd(&rowsum[(long)z * 2048 + rowg], psum[mi][r]);
        }
    }
  } else {
    u16 (*sm)[68] = (u16(*)[68])smem;
    int t = blk - ngemm;
    int b = t >> 9, r = t & 511;
    int j0 = (r & 15) << 6, i0 = ((r >> 4) & 31) << 6;
    const u16* s = Vb + (long)b * Sn * Dn;
    u16* d = vt + (long)b * Dn * Sn;
    int tx = tid & 15, r0 = tid >> 4;
    #pragma unroll
    for (int rr = r0; rr < 64; rr += 16) {
      ushort4 v = *(const ushort4*)&s[(long)(i0 + rr) * 1024 + j0 + tx * 4];
      sm[rr][tx*4+0] = v.x; sm[rr][tx*4+1] = v.y; sm[rr][tx*4+2] = v.z; sm[rr][tx*4+3] = v.w;
    }
    __syncthreads();
    #pragma unroll
    for (int cc = r0; cc < 64; cc += 16) {
      ushort4 o;
      o.x = sm[tx*4+0][cc]; o.y = sm[tx*4+1][cc];
      o.z = sm[tx*4+2][cc]; o.w = sm[tx*4+3][cc];
      *(ushort4*)&d[(long)(j0 + cc) * 2048 + i0 + tx * 4] = o;
    }
  }
}

// ==== smax_conv: small-ws fallback (softmax rows + grouped conv) ===========
__global__ __launch_bounds__(256)
void smax_conv(u16* __restrict__ pa, u16* __restrict__ pb, int rowsplit, int nsm,
               const float* __restrict__ x, const float* __restrict__ cw,
               const float* __restrict__ cb, u16* __restrict__ convo) {
  __shared__ u16 smem[22160];
  __shared__ float red[4];
  int blk = blockIdx.x;
  int tid = threadIdx.x;
  if (blk < nsm) {
    long row = blk;
    u16* p = (row < rowsplit) ? pa + row * 2048 : pb + (row - rowsplit) * 2048;
    ushort4 a = *(const ushort4*)&p[tid * 8];
    ushort4 b = *(const ushort4*)&p[tid * 8 + 4];
    float f0 = bf2f(a.x), f1 = bf2f(a.y), f2 = bf2f(a.z), f3 = bf2f(a.w);
    float f4 = bf2f(b.x), f5 = bf2f(b.y), f6 = bf2f(b.z), f7 = bf2f(b.w);
    float m = fmaxf(fmaxf(fmaxf(f0, f1), fmaxf(f2, f3)),
                    fmaxf(fmaxf(f4, f5), fmaxf(f6, f7)));
    m = block_allreduce_max(m, red, tid);
    float e0 = __expf(f0 - m), e1 = __expf(f1 - m), e2 = __expf(f2 - m), e3 = __expf(f3 - m);
    float e4 = __expf(f4 - m), e5 = __expf(f5 - m), e6 = __expf(f6 - m), e7 = __expf(f7 - m);
    float s = block_allreduce_sum(e0 + e1 + e2 + e3 + e4 + e5 + e6 + e7, red, tid);
    float inv = 1.0f / s;
    ushort4 o1, o2;
    o1.x = f2bf(e0 * inv); o1.y = f2bf(e1 * inv); o1.z = f2bf(e2 * inv); o1.w = f2bf(e3 * inv);
    o2.x = f2bf(e4 * inv); o2.y = f2bf(e5 * inv); o2.z = f2bf(e6 * inv); o2.w = f2bf(e7 * inv);
    *(ushort4*)&p[tid * 8] = o1;
    *(ushort4*)&p[tid * 8 + 4] = o2;
  } else {
    conv_body(smem, blk - nsm, tid, x, cw, cb, convo);
  }
}

// ============ pv_conv: PV GEMM (normalize) + conv riders (fallback) ========
__global__ __launch_bounds__(256, 2)
void pv_conv(int npv,
             const u16* __restrict__ Pd, const u16* __restrict__ Pw,
             const u16* __restrict__ vt, u16* __restrict__ attn,
             const float* __restrict__ rowsum,
             const float* __restrict__ x, const float* __restrict__ cw,
             const float* __restrict__ cb, u16* __restrict__ convo) {
  __shared__ u16 smem[22160];
  int blk = blockIdx.x;
  int tid = threadIdx.x;
  if (blk < npv) {
    int lane = tid & 63, wv = tid >> 6;
    int quad = lane >> 4, lm = lane & 15;
    int wr = wv >> 1, wc = wv & 1;
    int z = blk >> 7;
    long m0 = (long)(blk & 15) * 128, n0 = (long)((blk >> 4) & 7) * 128;
    const u16* A = (z < 2) ? Pd + (long)z * Sn * Sn : Pw + (long)(z - 2) * Sn * Sn;
    const u16* B = vt + (long)z * Dn * Sn;
    u16* C = attn + (long)z * Sn * Dn;
    f32x4 acc[4][4] = {};
    gemm_tile_acc(A, B, 2048, 2048, 2048, m0, n0, smem, tid, acc);
    float inv[4][4];
    #pragma unroll
    for (int mi = 0; mi < 4; mi++)
      #pragma unroll
      for (int r = 0; r < 4; r++) {
        long rowg = m0 + wr * 64 + mi * 16 + quad * 4 + r;
        inv[mi][r] = 1.0f / rowsum[(long)z * 2048 + rowg];
      }
    #pragma unroll
    for (int mi = 0; mi < 4; mi++) {
      #pragma unroll
      for (int ni = 0; ni < 4; ni++) {
        int col = (int)n0 + wc * 64 + ni * 16 + lm;
        #pragma unroll
        for (int r = 0; r < 4; r++) {
          long rowg = m0 + wr * 64 + mi * 16 + quad * 4 + r;
          C[rowg * 1024 + col] = f2bf(acc[mi][ni][r] * inv[mi][r]);
        }
      }
    }
  } else {
    conv_body(smem, blk - npv, tid, x, cw, cb, convo);
  }
}

// ================= ln2 standalone (fallback) =================
__global__ __launch_bounds__(256)
void ln2_kernel(const u16* __restrict__ conv, const u16* __restrict__ attn,
                const float* __restrict__ gamma, const float* __restrict__ beta,
                u16* __restrict__ out) {
  __shared__ float red[4];
  ln2_row(conv, attn, gamma, beta, out, blockIdx.x, threadIdx.x, red);
}

// ================= workspace layout =================
static const size_t OFF_WT    = 0;
static const size_t OFF_QKVB  = 8ull << 20;
static const size_t OFF_RSUM  = (8ull << 20) + (16 << 10);
static const size_t OFF_Q     = 9ull << 20;
static const size_t OFF_K     = 25ull << 20;
static const size_t OFF_V     = 41ull << 20;
static const size_t OFF_PW    = 57ull << 20;

extern "C" void kernel_launch(void* const* d_in, const int* in_sizes, int n_in,
                              void* d_out, int out_size, void* d_ws, size_t ws_size,
                              hipStream_t stream) {
  const float* x     = (const float*)d_in[0];
  const float* Wq    = (const float*)d_in[1];
  const float* bq    = (const float*)d_in[2];
  const float* Wk    = (const float*)d_in[3];
  const float* Wv    = (const float*)d_in[4];
  const float* bv    = (const float*)d_in[5];
  const float* cw    = (const float*)d_in[6];
  const float* cb    = (const float*)d_in[7];
  const float* gamma = (const float*)d_in[8];
  const float* beta  = (const float*)d_in[9];
  const float* Wo    = (const float*)d_in[10];
  const float* bo    = (const float*)d_in[11];
  float* out = (float*)d_out;
  char* ws = (char*)d_ws;

  u16*   wT    = (u16*)(ws + OFF_WT);
  float* qkvb  = (float*)(ws + OFF_QKVB);
  float* rsum  = (float*)(ws + OFF_RSUM);
  u16*   Qb    = (u16*)(ws + OFF_Q);
  u16*   Kb    = (u16*)(ws + OFF_K);
  u16*   Vb    = (u16*)(ws + OFF_V);
  u16*   Pw    = (u16*)(ws + OFF_PW);
  u16*   xb    = (u16*)d_out;               // dead after QKV; then P b0,1
  u16*   Pd    = (u16*)d_out;
  u16*   vt    = (u16*)d_out + 8388608;     // V^T, dead after PV
  u16*   conv  = Vb;                        // conv output
  u16*   attn  = Qb;
  u16*   combined = Kb;
  const long PBS = (long)Sn * Sn;

  dim3 tb(256);

  // 1. prologue: weights T + bias + rowsum zero + x cvt
  prep_all<<<dim3(9217), tb, 0, stream>>>(Wq, Wk, Wv, Wo, wT, bq, bv, qkvb,
                                          rsum, x, xb);

  if (ws_size >= (73ull << 20)) {
    // 2. cooperative fused pipeline (QKV -> scores+conv -> PV -> ln2 -> out)
    FusedArgs fa;
    fa.xb = xb; fa.wT = wT; fa.qkvb = qkvb;
    fa.Qb = Qb; fa.Kb = Kb; fa.vt = vt;
    fa.Pd = Pd; fa.Pw = Pw; fa.rsum = rsum;
    fa.x = x; fa.cw = cw; fa.cb = cb; fa.conv = conv;
    fa.attn = attn; fa.gamma = gamma; fa.beta = beta; fa.combined = combined;
    fa.bo = bo; fa.out = out;
    void* kargs[] = { (void*)&fa };
    hipError_t ce = hipLaunchCooperativeKernel(
        (const void*)fused_all, dim3(512), tb, kargs, 0, stream);
    if (ce != hipSuccess) {
      // fallback: proven r14 separate-launch sequence
      gemm_nt<u16><<<dim3(64, 8, 3), tb, 0, stream>>>(
          xb, nullptr, 0, 1024, wT, 1048576, 1024, Qb, (u16*)nullptr, 8388608,
          1024, 99, 1024, 1.0f, qkvb, 1024, nullptr, 0, 0, vt);
      post_qkv<<<dim3(1024), tb, 0, stream>>>(1024, Qb, Kb, Pd, Pw, Vb, vt, rsum);
      pv_conv<<<dim3(512 + 1024), tb, 0, stream>>>(512, Pd, Pw, vt, attn, rsum,
                                                   x, cw, cb, conv);
      ln2_kernel<<<dim3(8192), tb, 0, stream>>>(conv, attn, gamma, beta, combined);
      gemm_nt<float><<<dim3(64, 8, 1), tb, 0, stream>>>(
          combined, nullptr, 0, 1024, wT + 3u * 1048576u, 0, 1024,
          out, (float*)nullptr, 0, 1024,
          99, 1024, 1.0f, bo, 0, x, 0, 1024, nullptr);
    }
  } else {
    // small-ws fallback: classic flow (V normal, V^T riders, classic softmax)
    gemm_nt<u16><<<dim3(64, 8, 3), tb, 0, stream>>>(
        xb, nullptr, 0, 1024, wT, 1048576, 1024, Qb, (u16*)nullptr, 8388608,
        1024, 99, 1024, 1.0f, qkvb, 1024, nullptr, 0, 0, nullptr);
    post_qkv<<<dim3(2048), tb, 0, stream>>>(0, Qb, Kb, Pd, Pw, Vb, vt, rsum);
    for (int c = 0; c < 2; c++) {
      long off = (long)c * 2 * Sn * Dn;
      gemm_nt<u16><<<dim3(16, 16, 2), tb, 0, stream>>>(
          Qb + off, nullptr, (long)Sn * Dn, 1024, Kb + off, (long)Sn * Dn, 1024,
          Pd, (u16*)nullptr, PBS, 2048,
          99, 1024, 0.03125f, nullptr, 0, nullptr, 0, 0, nullptr);
      smax_conv<<<dim3(4096 + (c == 0 ? 1024 : 0)), tb, 0, stream>>>(
          Pd, Pd, 4096, 4096, x, cw, cb, conv);
      gemm_nt<u16><<<dim3(16, 8, 2), tb, 0, stream>>>(
          Pd, nullptr, PBS, 2048, vt + off, (long)Dn * Sn, 2048,
          attn + off, (u16*)nullptr, (long)Sn * Dn, 1024,
          99, 2048, 1.0f, nullptr, 0, nullptr, 0, 0, nullptr);
    }
    ln2_kernel<<<dim3(8192), tb, 0, stream>>>(conv, attn, gamma, beta, conv);
    ln2_kernel<<<dim3(8192), tb, 0, stream>>>(conv, attn, gamma, beta, combined);
  }
}

// Round 11
// 328.494 us; speedup vs baseline: 2.5161x; 2.5161x over previous
//
#include <hip/hip_runtime.h>
#include <cstdint>

// DynamicConvAttention: B=4, S=2048, D=1024, NH=16 (groups), K=3
// f32 I/O, bf16 MFMA internal. 6 launches (primary path).
//
// r19: RESUBMIT of r18 (round-10 bench failed on container acquisition —
// infra error, no measurement). No source changes.
// r18: the 329.4us round-6 kernel with ONE change: the 1024 light conv
// rider blocks move from pv_conv to the QKV launch's tail (grid z-planes
// 3,4; dispatched last -> fill QKV's 0.6-round ragged tail). pv_conv
// becomes a clean 512-block single round.
// Kept from prior rounds: unnormalized-exp softmax (P'=exp(s/32), f32
// rowsum atomics, normalize in PV epilogue); V written TRANSPOSED into
// vt directly by the QKV z=2 epilogue; fused LN2(LN1(conv)+attn).
//
// ws: wT[0,8M) | qkvb[8M,+12K) | rsum[8M+16K,+32K) | Q[9,25M) | K[25,41M)
//     | V[41,57M)=conv out | Pw[57,73M)
// d_out: xb/Pd [0,16Mi) | vt [16Mi,32Mi)

#define DEV __device__ __forceinline__

typedef unsigned short u16;
typedef __attribute__((ext_vector_type(8))) short bf16x8;
typedef __attribute__((ext_vector_type(4))) float f32x4;

static const int Sn = 2048, Dn = 1024;

DEV float bf2f(u16 u) { union { unsigned int i; float f; } w; w.i = ((unsigned int)u) << 16; return w.f; }
DEV u16 f2bf(float f) {
  union { float f; unsigned int i; } w; w.f = f;
  unsigned int x = w.i;
  return (u16)((x + 0x7FFFu + ((x >> 16) & 1u)) >> 16);
}

DEV void gload_lds16(const u16* gsrc, u16* lds_dst) {
  __builtin_amdgcn_global_load_lds(
      (const __attribute__((address_space(1))) void*)gsrc,
      (__attribute__((address_space(3))) void*)lds_dst,
      16, 0, 0);
}

DEV float block_allreduce_sum(float v, float* red, int tid) {
  #pragma unroll
  for (int o = 32; o > 0; o >>= 1) v += __shfl_down(v, o, 64);
  __syncthreads();
  if ((tid & 63) == 0) red[tid >> 6] = v;
  __syncthreads();
  return red[0] + red[1] + red[2] + red[3];
}

DEV float block_allreduce_max(float v, float* red, int tid) {
  #pragma unroll
  for (int o = 32; o > 0; o >>= 1) v = fmaxf(v, __shfl_down(v, o, 64));
  __syncthreads();
  if ((tid & 63) == 0) red[tid >> 6] = v;
  __syncthreads();
  return fmaxf(fmaxf(red[0], red[1]), fmaxf(red[2], red[3]));
}

// ---- grouped conv body (riders); smem = 22160 u16 ----
// out[s,oc] = cb[oc] + sum_k x[s+t-1, g*64+i]*w[oc, k=t*64+i]
DEV void conv_body(u16* smem, int r, int tid,
                   const float* __restrict__ x, const float* __restrict__ cw,
                   const float* __restrict__ cb, u16* __restrict__ convo) {
  u16 (*sx)[72] = (u16(*)[72])smem;
  u16 (*sw)[200] = (u16(*)[200])(smem + 9360);
  int s0 = (r & 15) * 128;
  int g = (r >> 4) & 15;
  int b = r >> 8;
  int lane = tid & 63, wv = tid >> 6;
  int quad = lane >> 4, lm = lane & 15;
  for (int idx = tid; idx < 64 * 192; idx += 256) {
    int oc = idx / 192, k = idx - oc * 192;
    int t2 = k >> 6, i = k & 63;
    sw[oc][k] = f2bf(cw[((long)(g * 64 + oc)) * 192 + i * 3 + t2]);
  }
  for (int idx = tid; idx < 130 * 16; idx += 256) {
    int rr = idx >> 4, c4 = (idx & 15) * 4;
    int s = s0 - 1 + rr;
    ushort4 v;
    if (s >= 0 && s < Sn) {
      float4 f = *(const float4*)&x[((long)b * Sn + s) * Dn + g * 64 + c4];
      v.x = f2bf(f.x); v.y = f2bf(f.y); v.z = f2bf(f.z); v.w = f2bf(f.w);
    } else { v.x = 0; v.y = 0; v.z = 0; v.w = 0; }
    *(ushort4*)&sx[rr][c4] = v;
  }
  __syncthreads();
  f32x4 acc[2][4] = {};
  #pragma unroll
  for (int ks = 0; ks < 6; ks++) {
    int t2 = ks >> 1;
    int i0 = (ks & 1) * 32 + quad * 8;
    bf16x8 a0 = *(const bf16x8*)&sx[wv * 32 + lm + t2][i0];
    bf16x8 a1 = *(const bf16x8*)&sx[wv * 32 + 16 + lm + t2][i0];
    #pragma unroll
    for (int nf = 0; nf < 4; nf++) {
      bf16x8 bf = *(const bf16x8*)&sw[nf * 16 + lm][ks * 32 + quad * 8];
      acc[0][nf] = __builtin_amdgcn_mfma_f32_16x16x32_bf16(a0, bf, acc[0][nf], 0, 0, 0);
      acc[1][nf] = __builtin_amdgcn_mfma_f32_16x16x32_bf16(a1, bf, acc[1][nf], 0, 0, 0);
    }
  }
  #pragma unroll
  for (int mi = 0; mi < 2; mi++) {
    #pragma unroll
    for (int nf = 0; nf < 4; nf++) {
      int col = g * 64 + nf * 16 + lm;
      float bias = cb[col];
      #pragma unroll
      for (int rr = 0; rr < 4; rr++) {
        int row = wv * 32 + mi * 16 + quad * 4 + rr;
        convo[((long)b * Sn + s0 + row) * Dn + col] = f2bf(acc[mi][nf][rr] + bias);
      }
    }
  }
}

// ================= prep_all: weights T + bias + rowsum zero + x cvt ========
__global__ __launch_bounds__(256)
void prep_all(const float* __restrict__ Wq, const float* __restrict__ Wk,
              const float* __restrict__ Wv, const float* __restrict__ Wo,
              u16* __restrict__ wT,
              const float* __restrict__ bq, const float* __restrict__ bv,
              float* __restrict__ qkvb, float* __restrict__ rowsum,
              const float* __restrict__ x, u16* __restrict__ xb) {
  __shared__ u16 sm[64][68];
  int blk = blockIdx.x;
  int tid = threadIdx.x;
  if (blk < 1024) {
    int w = blk >> 8, t = blk & 255;
    const float* src = (w == 0) ? Wq : (w == 1) ? Wk : (w == 2) ? Wv : Wo;
    u16* dst = wT + (size_t)w * 1048576u;
    int i0 = (t >> 4) << 6, j0 = (t & 15) << 6;
    int tx = tid & 15, r0 = tid >> 4;
    #pragma unroll
    for (int rr = r0; rr < 64; rr += 16) {
      float4 v = *(const float4*)&src[(long)(i0 + rr) * 1024 + j0 + tx * 4];
      sm[rr][tx*4+0] = f2bf(v.x); sm[rr][tx*4+1] = f2bf(v.y);
      sm[rr][tx*4+2] = f2bf(v.z); sm[rr][tx*4+3] = f2bf(v.w);
    }
    __syncthreads();
    #pragma unroll
    for (int cc = r0; cc < 64; cc += 16) {
      ushort4 o;
      o.x = sm[tx*4+0][cc]; o.y = sm[tx*4+1][cc];
      o.z = sm[tx*4+2][cc]; o.w = sm[tx*4+3][cc];
      *(ushort4*)&dst[(long)(j0 + cc) * 1024 + i0 + tx * 4] = o;
    }
  } else if (blk == 1024) {
    for (int j = tid; j < 3072; j += 256) {
      float v = 0.0f;
      if (j < 1024) v = bq[j];
      else if (j >= 2048) v = bv[j - 2048];
      qkvb[j] = v;
    }
    for (int j = tid; j < 8192; j += 256) rowsum[j] = 0.0f;
  } else {
    int i = (blk - 1025) * 1024 + tid * 4;
    float4 v = *(const float4*)&x[i];
    ushort4 o;
    o.x = f2bf(v.x); o.y = f2bf(v.y); o.z = f2bf(v.z); o.w = f2bf(v.w);
    *(ushort4*)&xb[i] = o;
  }
}

// ================= NT GEMM, BK=64 split-halves (proven r7 core) ============
// vtout: if non-null and z==2 (bf16 out), epilogue writes tile TRANSPOSED
// into vtout[b][d][s]. z>=3 planes (when convo non-null) are conv riders:
// r = bx + by*64 + (z-3)*512, dispatched last -> fill the QKV tail.
template<typename CT>
__global__ __launch_bounds__(256, 2)
void gemm_nt(const u16* __restrict__ A, const u16* __restrict__ A2, long Abs, int lda,
             const u16* __restrict__ B, long Bbs, int ldb,
             CT* __restrict__ C, CT* __restrict__ C2, long Cbs, int ldc,
             int zsplit, int K, float scale,
             const float* __restrict__ bias, int bias_bs,
             const float* __restrict__ res, long Rbs, int ldr,
             u16* __restrict__ vtout,
             const float* __restrict__ cx, const float* __restrict__ cw,
             const float* __restrict__ cb, u16* __restrict__ convo) {
  __shared__ u16 smem[22160];  // gemm uses first 16384 u16; conv uses 22160
  int tid = threadIdx.x;
  int z = blockIdx.z;
  if (convo && z >= 3) {
    int r = (int)blockIdx.x + (int)blockIdx.y * 64 + (z - 3) * 512;
    conv_body(smem, r, tid, cx, cw, cb, convo);
    return;
  }
  u16* sA0 = smem;                     // [2][128*32]
  u16* sB0 = smem + 2 * 128 * 32;      // [2][128*32]
  int lane = tid & 63, wv = tid >> 6;
  int quad = lane >> 4, lm = lane & 15;
  int wr = wv >> 1, wc = wv & 1;
  long m0 = (long)blockIdx.x * 128, n0 = (long)blockIdx.y * 128;
  if (z >= zsplit) { A = A2 + (long)(z - zsplit) * Abs; C = C2 + (long)(z - zsplit) * Cbs; }
  else             { A = A  + (long)z * Abs;            C = C  + (long)z * Cbs; }
  B += (long)z * Bbs;
  if (res) res += (long)z * Rbs;

  f32x4 acc[4][4] = {};

  int srow = wv * 16 + (lane >> 2);
  int sch = (lane & 3) * 8;
  const u16* Ap = A + (m0 + srow) * (long)lda + sch;
  const u16* Bp = B + (n0 + srow) * (long)ldb + sch;
  const int lofs = wv * 16 * 32;

  for (int k0 = 0; k0 < K; k0 += 64) {
    #pragma unroll
    for (int h = 0; h < 2; h++) {
      int kh = k0 + h * 32;
      gload_lds16(Ap + kh, &sA0[h * 128 * 32 + lofs]);
      gload_lds16(Ap + 64 * (long)lda + kh, &sA0[h * 128 * 32 + lofs + 64 * 32]);
      gload_lds16(Bp + kh, &sB0[h * 128 * 32 + lofs]);
      gload_lds16(Bp + 64 * (long)ldb + kh, &sB0[h * 128 * 32 + lofs + 64 * 32]);
    }
    __syncthreads();
    #pragma unroll
    for (int h = 0; h < 2; h++) {
      bf16x8 af[4], bfr[4];
      #pragma unroll
      for (int mi = 0; mi < 4; mi++)
        af[mi] = *(const bf16x8*)&sA0[h * 128 * 32 + (wr * 64 + mi * 16 + lm) * 32 + quad * 8];
      #pragma unroll
      for (int ni = 0; ni < 4; ni++)
        bfr[ni] = *(const bf16x8*)&sB0[h * 128 * 32 + (wc * 64 + ni * 16 + lm) * 32 + quad * 8];
      #pragma unroll
      for (int mi = 0; mi < 4; mi++)
        #pragma unroll
        for (int ni = 0; ni < 4; ni++)
          acc[mi][ni] = __builtin_amdgcn_mfma_f32_16x16x32_bf16(af[mi], bfr[ni], acc[mi][ni], 0, 0, 0);
    }
    __syncthreads();
  }

  if (sizeof(CT) == 2 && vtout && z == 2) {
    int b = (int)(m0 >> 11);
    long s0 = (m0 & 2047) + wr * 64 + quad * 4;
    #pragma unroll
    for (int ni = 0; ni < 4; ni++) {
      int col = (int)n0 + wc * 64 + ni * 16 + lm;
      float bv = bias ? bias[(long)z * bias_bs + col] : 0.0f;
      u16* vrow = vtout + ((long)b * 1024 + col) * 2048;
      #pragma unroll
      for (int mi = 0; mi < 4; mi++) {
        ushort4 o;
        o.x = f2bf(acc[mi][ni][0] * scale + bv);
        o.y = f2bf(acc[mi][ni][1] * scale + bv);
        o.z = f2bf(acc[mi][ni][2] * scale + bv);
        o.w = f2bf(acc[mi][ni][3] * scale + bv);
        *(ushort4*)&vrow[s0 + mi * 16] = o;
      }
    }
  } else {
    #pragma unroll
    for (int mi = 0; mi < 4; mi++) {
      #pragma unroll
      for (int ni = 0; ni < 4; ni++) {
        int col = (int)n0 + wc * 64 + ni * 16 + lm;
        float bv = bias ? bias[(long)z * bias_bs + col] : 0.0f;
        #pragma unroll
        for (int r = 0; r < 4; r++) {
          long rowg = m0 + wr * 64 + mi * 16 + quad * 4 + r;
          float v = acc[mi][ni][r] * scale + bv;
          if (res) v += res[rowg * (long)ldr + col];
          if constexpr (sizeof(CT) == 2) C[rowg * (long)ldc + col] = f2bf(v);
          else                           C[rowg * (long)ldc + col] = v;
        }
      }
    }
  }
}

// ====== post_qkv: scores GEMM (exp + rowsum) [+ V^T tiles, fallback] ======
__global__ __launch_bounds__(256, 2)
void post_qkv(int ngemm,
              const u16* __restrict__ Qb, const u16* __restrict__ Kb,
              u16* __restrict__ Pd, u16* __restrict__ Pw,
              const u16* __restrict__ Vb, u16* __restrict__ vt,
              float* __restrict__ rowsum) {
  __shared__ u16 smem[2 * 2 * 128 * 32];  // 32 KB
  int blk = blockIdx.x;
  int tid = threadIdx.x;
  if (blk < ngemm) {
    u16* sA0 = smem;
    u16* sB0 = smem + 2 * 128 * 32;
    int lane = tid & 63, wv = tid >> 6;
    int quad = lane >> 4, lm = lane & 15;
    int wr = wv >> 1, wc = wv & 1;
    int z = blk >> 8;
    long m0 = (long)(blk & 15) * 128, n0 = (long)((blk >> 4) & 15) * 128;
    const u16* A = Qb + (long)z * Sn * Dn;
    const u16* B = Kb + (long)z * Sn * Dn;
    u16* C = (z < 2) ? Pd + (long)z * Sn * Sn : Pw + (long)(z - 2) * Sn * Sn;

    f32x4 acc[4][4] = {};
    int srow = wv * 16 + (lane >> 2);
    int sch = (lane & 3) * 8;
    const u16* Ap = A + (m0 + srow) * 1024 + sch;
    const u16* Bp = B + (n0 + srow) * 1024 + sch;
    const int lofs = wv * 16 * 32;

    for (int k0 = 0; k0 < 1024; k0 += 64) {
      #pragma unroll
      for (int h = 0; h < 2; h++) {
        int kh = k0 + h * 32;
        gload_lds16(Ap + kh, &sA0[h * 128 * 32 + lofs]);
        gload_lds16(Ap + 64 * 1024 + kh, &sA0[h * 128 * 32 + lofs + 64 * 32]);
        gload_lds16(Bp + kh, &sB0[h * 128 * 32 + lofs]);
        gload_lds16(Bp + 64 * 1024 + kh, &sB0[h * 128 * 32 + lofs + 64 * 32]);
      }
      __syncthreads();
      #pragma unroll
      for (int h = 0; h < 2; h++) {
        bf16x8 af[4], bfr[4];
        #pragma unroll
        for (int mi = 0; mi < 4; mi++)
          af[mi] = *(const bf16x8*)&sA0[h * 128 * 32 + (wr * 64 + mi * 16 + lm) * 32 + quad * 8];
        #pragma unroll
        for (int ni = 0; ni < 4; ni++)
          bfr[ni] = *(const bf16x8*)&sB0[h * 128 * 32 + (wc * 64 + ni * 16 + lm) * 32 + quad * 8];
        #pragma unroll
        for (int mi = 0; mi < 4; mi++)
          #pragma unroll
          for (int ni = 0; ni < 4; ni++)
            acc[mi][ni] = __builtin_amdgcn_mfma_f32_16x16x32_bf16(af[mi], bfr[ni], acc[mi][ni], 0, 0, 0);
      }
      __syncthreads();
    }
    float psum[4][4];
    #pragma unroll
    for (int mi = 0; mi < 4; mi++)
      #pragma unroll
      for (int r = 0; r < 4; r++) psum[mi][r] = 0.0f;
    #pragma unroll
    for (int mi = 0; mi < 4; mi++) {
      #pragma unroll
      for (int ni = 0; ni < 4; ni++) {
        int col = (int)n0 + wc * 64 + ni * 16 + lm;
        #pragma unroll
        for (int r = 0; r < 4; r++) {
          long rowg = m0 + wr * 64 + mi * 16 + quad * 4 + r;
          float e = __expf(acc[mi][ni][r] * 0.03125f);
          psum[mi][r] += e;
          C[rowg * 2048 + col] = f2bf(e);
        }
      }
    }
    #pragma unroll
    for (int mi = 0; mi < 4; mi++)
      #pragma unroll
      for (int r = 0; r < 4; r++) {
        float v = psum[mi][r];
        v += __shfl_xor(v, 1, 64);
        v += __shfl_xor(v, 2, 64);
        v += __shfl_xor(v, 4, 64);
        v += __shfl_xor(v, 8, 64);
        psum[mi][r] = v;
      }
    if (lm == 0) {
      #pragma unroll
      for (int mi = 0; mi < 4; mi++)
        #pragma unroll
        for (int r = 0; r < 4; r++) {
          long rowg = m0 + wr * 64 + mi * 16 + quad * 4 + r;
          unsafeAtomicAdd(&rowsum[(long)z * 2048 + rowg], psum[mi][r]);
        }
    }
  } else {
    u16 (*sm)[68] = (u16(*)[68])smem;
    int t = blk - ngemm;
    int b = t >> 9, r = t & 511;
    int j0 = (r & 15) << 6, i0 = ((r >> 4) & 31) << 6;
    const u16* s = Vb + (long)b * Sn * Dn;
    u16* d = vt + (long)b * Dn * Sn;
    int tx = tid & 15, r0 = tid >> 4;
    #pragma unroll
    for (int rr = r0; rr < 64; rr += 16) {
      ushort4 v = *(const ushort4*)&s[(long)(i0 + rr) * 1024 + j0 + tx * 4];
      sm[rr][tx*4+0] = v.x; sm[rr][tx*4+1] = v.y; sm[rr][tx*4+2] = v.z; sm[rr][tx*4+3] = v.w;
    }
    __syncthreads();
    #pragma unroll
    for (int cc = r0; cc < 64; cc += 16) {
      ushort4 o;
      o.x = sm[tx*4+0][cc]; o.y = sm[tx*4+1][cc];
      o.z = sm[tx*4+2][cc]; o.w = sm[tx*4+3][cc];
      *(ushort4*)&d[(long)(j0 + cc) * 2048 + i0 + tx * 4] = o;
    }
  }
}

// ==== smax_conv: kept for fallback (softmax rows + grouped conv) ===========
__global__ __launch_bounds__(256)
void smax_conv(u16* __restrict__ pa, u16* __restrict__ pb, int rowsplit, int nsm,
               const float* __restrict__ x, const float* __restrict__ cw,
               const float* __restrict__ cb, u16* __restrict__ convo) {
  __shared__ u16 smem[22160];
  __shared__ float red[4];
  int blk = blockIdx.x;
  int tid = threadIdx.x;
  if (blk < nsm) {
    long row = blk;
    u16* p = (row < rowsplit) ? pa + row * 2048 : pb + (row - rowsplit) * 2048;
    ushort4 a = *(const ushort4*)&p[tid * 8];
    ushort4 b = *(const ushort4*)&p[tid * 8 + 4];
    float f0 = bf2f(a.x), f1 = bf2f(a.y), f2 = bf2f(a.z), f3 = bf2f(a.w);
    float f4 = bf2f(b.x), f5 = bf2f(b.y), f6 = bf2f(b.z), f7 = bf2f(b.w);
    float m = fmaxf(fmaxf(fmaxf(f0, f1), fmaxf(f2, f3)),
                    fmaxf(fmaxf(f4, f5), fmaxf(f6, f7)));
    m = block_allreduce_max(m, red, tid);
    float e0 = __expf(f0 - m), e1 = __expf(f1 - m), e2 = __expf(f2 - m), e3 = __expf(f3 - m);
    float e4 = __expf(f4 - m), e5 = __expf(f5 - m), e6 = __expf(f6 - m), e7 = __expf(f7 - m);
    float s = block_allreduce_sum(e0 + e1 + e2 + e3 + e4 + e5 + e6 + e7, red, tid);
    float inv = 1.0f / s;
    ushort4 o1, o2;
    o1.x = f2bf(e0 * inv); o1.y = f2bf(e1 * inv); o1.z = f2bf(e2 * inv); o1.w = f2bf(e3 * inv);
    o2.x = f2bf(e4 * inv); o2.y = f2bf(e5 * inv); o2.z = f2bf(e6 * inv); o2.w = f2bf(e7 * inv);
    *(ushort4*)&p[tid * 8] = o1;
    *(ushort4*)&p[tid * 8 + 4] = o2;
  } else {
    conv_body(smem, blk - nsm, tid, x, cw, cb, convo);
  }
}

// ============ pv_conv: PV GEMM (normalize epilogue) [+ conv riders] ========
__global__ __launch_bounds__(256, 2)
void pv_conv(int npv,
             const u16* __restrict__ Pd, const u16* __restrict__ Pw,
             const u16* __restrict__ vt, u16* __restrict__ attn,
             const float* __restrict__ rowsum,
             const float* __restrict__ x, const float* __restrict__ cw,
             const float* __restrict__ cb, u16* __restrict__ convo) {
  __shared__ u16 smem[22160];
  int blk = blockIdx.x;
  int tid = threadIdx.x;
  if (blk < npv) {
    u16* sA0 = smem;
    u16* sB0 = smem + 2 * 128 * 32;
    int lane = tid & 63, wv = tid >> 6;
    int quad = lane >> 4, lm = lane & 15;
    int wr = wv >> 1, wc = wv & 1;
    int z = blk >> 7;
    long m0 = (long)(blk & 15) * 128, n0 = (long)((blk >> 4) & 7) * 128;
    const u16* A = (z < 2) ? Pd + (long)z * Sn * Sn : Pw + (long)(z - 2) * Sn * Sn;
    const u16* B = vt + (long)z * Dn * Sn;
    u16* C = attn + (long)z * Sn * Dn;

    f32x4 acc[4][4] = {};
    int srow = wv * 16 + (lane >> 2);
    int sch = (lane & 3) * 8;
    const u16* Ap = A + (m0 + srow) * 2048 + sch;
    const u16* Bp = B + (n0 + srow) * 2048 + sch;
    const int lofs = wv * 16 * 32;

    for (int k0 = 0; k0 < 2048; k0 += 64) {
      #pragma unroll
      for (int h = 0; h < 2; h++) {
        int kh = k0 + h * 32;
        gload_lds16(Ap + kh, &sA0[h * 128 * 32 + lofs]);
        gload_lds16(Ap + 64 * 2048 + kh, &sA0[h * 128 * 32 + lofs + 64 * 32]);
        gload_lds16(Bp + kh, &sB0[h * 128 * 32 + lofs]);
        gload_lds16(Bp + 64 * 2048 + kh, &sB0[h * 128 * 32 + lofs + 64 * 32]);
      }
      __syncthreads();
      #pragma unroll
      for (int h = 0; h < 2; h++) {
        bf16x8 af[4], bfr[4];
        #pragma unroll
        for (int mi = 0; mi < 4; mi++)
          af[mi] = *(const bf16x8*)&sA0[h * 128 * 32 + (wr * 64 + mi * 16 + lm) * 32 + quad * 8];
        #pragma unroll
        for (int ni = 0; ni < 4; ni++)
          bfr[ni] = *(const bf16x8*)&sB0[h * 128 * 32 + (wc * 64 + ni * 16 + lm) * 32 + quad * 8];
        #pragma unroll
        for (int mi = 0; mi < 4; mi++)
          #pragma unroll
          for (int ni = 0; ni < 4; ni++)
            acc[mi][ni] = __builtin_amdgcn_mfma_f32_16x16x32_bf16(af[mi], bfr[ni], acc[mi][ni], 0, 0, 0);
      }
      __syncthreads();
    }
    float inv[4][4];
    #pragma unroll
    for (int mi = 0; mi < 4; mi++)
      #pragma unroll
      for (int r = 0; r < 4; r++) {
        long rowg = m0 + wr * 64 + mi * 16 + quad * 4 + r;
        inv[mi][r] = 1.0f / rowsum[(long)z * 2048 + rowg];
      }
    #pragma unroll
    for (int mi = 0; mi < 4; mi++) {
      #pragma unroll
      for (int ni = 0; ni < 4; ni++) {
        int col = (int)n0 + wc * 64 + ni * 16 + lm;
        #pragma unroll
        for (int r = 0; r < 4; r++) {
          long rowg = m0 + wr * 64 + mi * 16 + quad * 4 + r;
          C[rowg * 1024 + col] = f2bf(acc[mi][ni][r] * inv[mi][r]);
        }
      }
    }
  } else {
    conv_body(smem, blk - npv, tid, x, cw, cb, convo);
  }
}

// ======== ln2: combined = LN2(LN1(conv) + attn), LN1 in f32, one pass ======
__global__ __launch_bounds__(256)
void ln2_kernel(const u16* __restrict__ conv, const u16* __restrict__ attn,
                const float* __restrict__ gamma, const float* __restrict__ beta,
                u16* __restrict__ out) {
  __shared__ float red[4];
  int tid = threadIdx.x;
  long base = (long)blockIdx.x * Dn + tid * 4;
  ushort4 cv = *(const ushort4*)&conv[base];
  float c0 = bf2f(cv.x), c1 = bf2f(cv.y), c2 = bf2f(cv.z), c3 = bf2f(cv.w);
  float4 gv = *(const float4*)&gamma[tid * 4];
  float4 bev = *(const float4*)&beta[tid * 4];
  float s1 = block_allreduce_sum(c0 + c1 + c2 + c3, red, tid);
  float mean1 = s1 * (1.0f / 1024.0f);
  float d0 = c0 - mean1, d1 = c1 - mean1, d2 = c2 - mean1, d3 = c3 - mean1;
  float sq1 = block_allreduce_sum(d0 * d0 + d1 * d1 + d2 * d2 + d3 * d3, red, tid);
  float inv1 = 1.0f / (sqrtf(sq1 * (1.0f / 1023.0f)) + 1e-6f);
  ushort4 av = *(const ushort4*)&attn[base];
  float v0 = gv.x * d0 * inv1 + bev.x + bf2f(av.x);
  float v1 = gv.y * d1 * inv1 + bev.y + bf2f(av.y);
  float v2 = gv.z * d2 * inv1 + bev.z + bf2f(av.z);
  float v3 = gv.w * d3 * inv1 + bev.w + bf2f(av.w);
  float s2 = block_allreduce_sum(v0 + v1 + v2 + v3, red, tid);
  float mean2 = s2 * (1.0f / 1024.0f);
  float e0 = v0 - mean2, e1 = v1 - mean2, e2 = v2 - mean2, e3 = v3 - mean2;
  float sq2 = block_allreduce_sum(e0 * e0 + e1 * e1 + e2 * e2 + e3 * e3, red, tid);
  float inv2 = 1.0f / (sqrtf(sq2 * (1.0f / 1023.0f)) + 1e-6f);
  ushort4 o;
  o.x = f2bf(gv.x * e0 * inv2 + bev.x);
  o.y = f2bf(gv.y * e1 * inv2 + bev.y);
  o.z = f2bf(gv.z * e2 * inv2 + bev.z);
  o.w = f2bf(gv.w * e3 * inv2 + bev.w);
  *(ushort4*)&out[base] = o;
}

// ================= workspace layout =================
static const size_t OFF_WT    = 0;
static const size_t OFF_QKVB  = 8ull << 20;
static const size_t OFF_RSUM  = (8ull << 20) + (16 << 10);
static const size_t OFF_Q     = 9ull << 20;
static const size_t OFF_K     = 25ull << 20;
static const size_t OFF_V     = 41ull << 20;
static const size_t OFF_PW    = 57ull << 20;

extern "C" void kernel_launch(void* const* d_in, const int* in_sizes, int n_in,
                              void* d_out, int out_size, void* d_ws, size_t ws_size,
                              hipStream_t stream) {
  const float* x     = (const float*)d_in[0];
  const float* Wq    = (const float*)d_in[1];
  const float* bq    = (const float*)d_in[2];
  const float* Wk    = (const float*)d_in[3];
  const float* Wv    = (const float*)d_in[4];
  const float* bv    = (const float*)d_in[5];
  const float* cw    = (const float*)d_in[6];
  const float* cb    = (const float*)d_in[7];
  const float* gamma = (const float*)d_in[8];
  const float* beta  = (const float*)d_in[9];
  const float* Wo    = (const float*)d_in[10];
  const float* bo    = (const float*)d_in[11];
  float* out = (float*)d_out;
  char* ws = (char*)d_ws;

  u16*   wT    = (u16*)(ws + OFF_WT);
  float* qkvb  = (float*)(ws + OFF_QKVB);
  float* rsum  = (float*)(ws + OFF_RSUM);
  u16*   Qb    = (u16*)(ws + OFF_Q);
  u16*   Kb    = (u16*)(ws + OFF_K);
  u16*   Vb    = (u16*)(ws + OFF_V);
  u16*   Pw    = (u16*)(ws + OFF_PW);
  u16*   xb    = (u16*)d_out;               // dead after QKV; then P b0,1
  u16*   Pd    = (u16*)d_out;
  u16*   vt    = (u16*)d_out + 8388608;     // V^T, dead after PV
  u16*   conv  = Vb;                        // conv output (Vb unused otherwise)
  u16*   attn  = Qb;
  u16*   combined = Kb;
  const long PBS = (long)Sn * Sn;

  dim3 tb(256);

  // 1. prologue: weights T + bias + rowsum zero + x cvt
  prep_all<<<dim3(9217), tb, 0, stream>>>(Wq, Wk, Wv, Wo, wT, bq, bv, qkvb,
                                          rsum, x, xb);

  if (ws_size >= (73ull << 20)) {
    // 2. QKV (z=0,1 -> Qb,Kb; z=2 -> vt transposed) + conv riders (z=3,4)
    gemm_nt<u16><<<dim3(64, 8, 5), tb, 0, stream>>>(
        xb, nullptr, 0, 1024, wT, 1048576, 1024, Qb, (u16*)nullptr, 8388608, 1024,
        99, 1024, 1.0f, qkvb, 1024, nullptr, 0, 0, vt,
        x, cw, cb, conv);
    // 3. scores GEMM (exp + rowsum epilogue), bare 1024 blocks
    post_qkv<<<dim3(1024), tb, 0, stream>>>(1024, Qb, Kb, Pd, Pw, Vb, vt, rsum);
    // 4. PV (512 tiles = 1 clean round, 1/rowsum epilogue)
    pv_conv<<<dim3(512), tb, 0, stream>>>(512, Pd, Pw, vt, attn, rsum,
                                          x, cw, cb, conv);
    // 5. combined = LN2(LN1(conv) + attn)
    ln2_kernel<<<dim3(8192), tb, 0, stream>>>(conv, attn, gamma, beta, combined);
  } else {
    // fallback: classic flow (V written normally, V^T rider pass, softmax)
    gemm_nt<u16><<<dim3(64, 8, 3), tb, 0, stream>>>(
        xb, nullptr, 0, 1024, wT, 1048576, 1024, Qb, (u16*)nullptr, 8388608, 1024,
        99, 1024, 1.0f, qkvb, 1024, nullptr, 0, 0, nullptr,
        nullptr, nullptr, nullptr, nullptr);
    post_qkv<<<dim3(2048), tb, 0, stream>>>(0, Qb, Kb, Pd, Pw, Vb, vt, rsum);
    for (int c = 0; c < 2; c++) {
      long off = (long)c * 2 * Sn * Dn;
      gemm_nt<u16><<<dim3(16, 16, 2), tb, 0, stream>>>(
          Qb + off, nullptr, (long)Sn * Dn, 1024, Kb + off, (long)Sn * Dn, 1024,
          Pd, (u16*)nullptr, PBS, 2048,
          99, 1024, 0.03125f, nullptr, 0, nullptr, 0, 0, nullptr,
          nullptr, nullptr, nullptr, nullptr);
      smax_conv<<<dim3(4096 + (c == 0 ? 1024 : 0)), tb, 0, stream>>>(
          Pd, Pd, 4096, 4096, x, cw, cb, conv);
      gemm_nt<u16><<<dim3(16, 8, 2), tb, 0, stream>>>(
          Pd, nullptr, PBS, 2048, vt + off, (long)Dn * Sn, 2048,
          attn + off, (u16*)nullptr, (long)Sn * Dn, 1024,
          99, 2048, 1.0f, nullptr, 0, nullptr, 0, 0, nullptr,
          nullptr, nullptr, nullptr, nullptr);
    }
    ln2_kernel<<<dim3(8192), tb, 0, stream>>>(conv, attn, gamma, beta, combined);
  }

  // 6. out = combined @ Wo + bo + x
  gemm_nt<float><<<dim3(64, 8, 1), tb, 0, stream>>>(
      combined, nullptr, 0, 1024, wT + 3u * 1048576u, 0, 1024,
      out, (float*)nullptr, 0, 1024,
      99, 1024, 1.0f, bo, 0, x, 0, 1024, nullptr,
      nullptr, nullptr, nullptr, nullptr);
}